// Round 6
// baseline (116.443 us; speedup 1.0000x reference)
//
#include <hip/hip_runtime.h>
#include <hip/hip_bf16.h>
#include <math.h>

typedef __attribute__((ext_vector_type(8))) short bf16x8;
typedef __attribute__((ext_vector_type(4))) float f32x4;

#define B_   16
#define C_   64
#define C1_  8
#define C2_  32
#define HW_  4096
#define M_   1024
#define LOG2E 1.4426950408889634f
#define MFMA_BF16 __builtin_amdgcn_mfma_f32_16x16x32_bf16

__device__ __forceinline__ unsigned short f2bf(float f) {
  union { float f; unsigned u; } v; v.f = f;
  unsigned r = (v.u + 0x7fffu + ((v.u >> 16) & 1u)) >> 16;
  return (unsigned short)r;
}
__device__ __forceinline__ float bf2f(unsigned short h) {
  union { unsigned u; float f; } v; v.u = ((unsigned)h) << 16;
  return v.f;
}

// ---------------------------------------------------------------------------
// K1: delta + phi + g2.  w_last is folded into g here:
//   g2[m][co] = sum_c (pooled_g[m][c] + b_g[c]) * w_last[co][c]   (f32 acc)
// stored bf16 transposed as g2_t[b][co(64)][m].  k_attn's PV then directly
// yields the final-conv numerator; its 512-FMA/thread epilogue disappears.
//   delta_s[b][n][16] : [dh(8) dl(8)] hi/lo split, LOG2E prefolded
//   phi_s[b][m][16]   : [ph(8) pl(8)] hi/lo split
// ---------------------------------------------------------------------------
__global__ __launch_bounds__(256, 4)
void k_pre(const float* __restrict__ x,
           const float* __restrict__ w_delta, const float* __restrict__ b_delta,
           const float* __restrict__ w_phi, const float* __restrict__ b_phi,
           const float* __restrict__ w_g,   const float* __restrict__ b_g,
           const float* __restrict__ w_last,
           unsigned short* __restrict__ delta_s,
           unsigned short* __restrict__ phi_s,
           unsigned short* __restrict__ g2_t) {
  __shared__ float comb[2*64*49];     // combine tree; rows 0..15 reused as agl
  __shared__ float wlds[64*33];       // w_last staged, padded (bank-free)
  int tid = threadIdx.x;

  // stage w_last once (8 coalesced loads/thread), consumed after barrier 4
  #pragma unroll
  for (int k = 0; k < 8; ++k) {
    int e = tid + k*256;              // e = co*32 + c
    wlds[(e >> 5)*33 + (e & 31)] = w_last[e];
  }

  int qt  = tid >> 6;              // channel quarter == wave index
  int sub = tid & 63;
  int id  = blockIdx.x * 64 + sub; // pixel id 0..65535
  int pix = id & 3;                // 2x2 corner (lane bits 0..1)
  int pm  = id >> 2;
  int b = pm >> 10;
  int m = pm & 1023;
  int py = 2*(m >> 5) + (pix >> 1);
  int px = 2*(m & 31) + (pix & 1);
  int n = py * 64 + px;

  int c0 = __builtin_amdgcn_readfirstlane(qt << 4);

  const float* xp = x + ((size_t)b*C_ + c0)*HW_ + n;
  float xv[16];
  #pragma unroll
  for (int i = 0; i < 16; ++i) xv[i] = xp[(size_t)i * HW_];

  float ad[8], ap[8], ag[32];
  #pragma unroll
  for (int o = 0; o < 8; ++o) {
    const float* wd = w_delta + o*C_ + c0;   // uniform -> s_load
    float a = 0.f;
    #pragma unroll
    for (int i = 0; i < 16; ++i) a += xv[i]*wd[i];
    ad[o] = a;
  }
  #pragma unroll
  for (int o = 0; o < 8; ++o) {
    const float* wp = w_phi + o*C_ + c0;     // uniform -> s_load
    float a = 0.f;
    #pragma unroll
    for (int i = 0; i < 16; ++i) a += xv[i]*wp[i];
    ap[o] = a;
  }
  #pragma unroll
  for (int o = 0; o < 32; ++o) {
    const float* wg = w_g + o*C_ + c0;       // uniform -> s_load
    float a = 0.f;
    #pragma unroll
    for (int i = 0; i < 16; ++i) a += xv[i]*wg[i];
    ag[o] = a;
  }

  if (qt == 1 || qt == 3) {
    float* cb = comb + (((qt >> 1)*64) + sub)*49;
    #pragma unroll
    for (int o = 0; o < 8; ++o) cb[o] = ad[o];
    #pragma unroll
    for (int o = 0; o < 8; ++o) cb[8+o] = ap[o];
    #pragma unroll
    for (int o = 0; o < 32; ++o) cb[16+o] = ag[o];
  }
  __syncthreads();
  if (qt == 0 || qt == 2) {
    const float* cb = comb + (((qt >> 1)*64) + sub)*49;
    #pragma unroll
    for (int o = 0; o < 8; ++o) ad[o] += cb[o];
    #pragma unroll
    for (int o = 0; o < 8; ++o) ap[o] += cb[8+o];
    #pragma unroll
    for (int o = 0; o < 32; ++o) ag[o] += cb[16+o];
  }
  __syncthreads();
  if (qt == 2) {
    float* cb = comb + sub*49;
    #pragma unroll
    for (int o = 0; o < 8; ++o) cb[o] = ad[o];
    #pragma unroll
    for (int o = 0; o < 8; ++o) cb[8+o] = ap[o];
    #pragma unroll
    for (int o = 0; o < 32; ++o) cb[16+o] = ag[o];
  }
  __syncthreads();
  if (qt == 0) {
    const float* cb = comb + sub*49;
    #pragma unroll
    for (int o = 0; o < 8; ++o) ad[o] += cb[o];
    #pragma unroll
    for (int o = 0; o < 8; ++o) ap[o] += cb[8+o];
    #pragma unroll
    for (int o = 0; o < 32; ++o) ag[o] += cb[16+o];

    // ---- delta: full-resolution, every lane writes its pixel (no pooling)
    {
      union { unsigned short s[8]; uint4 v; } dh, dl;
      #pragma unroll
      for (int o = 0; o < 8; ++o) {
        float v = (ad[o] + b_delta[o]) * LOG2E;
        unsigned short hi = f2bf(v);
        dh.s[o] = hi;
        dl.s[o] = f2bf(v - bf2f(hi));
      }
      uint4* dp = (uint4*)(delta_s + ((size_t)b*HW_ + n)*16);
      dp[0] = dh.v;
      dp[1] = dl.v;
    }

    // ---- phi/g: 2x2 shuffle max-pool
    #pragma unroll
    for (int o = 0; o < 8; ++o) {
      float v = ap[o];
      v = fmaxf(v, __shfl_xor(v, 1));
      v = fmaxf(v, __shfl_xor(v, 2));
      ap[o] = v;
    }
    #pragma unroll
    for (int o = 0; o < 32; ++o) {
      float v = ag[o];
      v = fmaxf(v, __shfl_xor(v, 1));
      v = fmaxf(v, __shfl_xor(v, 2));
      ag[o] = v;
    }

    if ((sub & 3) == 0) {
      #pragma unroll
      for (int cp = 0; cp < 8; ++cp) {
        int f = cp*16 + b;
        float v = ap[cp] + b_phi[cp];
        unsigned short hi = f2bf(v);
        unsigned short* pr = phi_s + ((size_t)(f >> 3)*M_ + m)*16;
        pr[f & 7]       = hi;
        pr[8 + (f & 7)] = f2bf(v - bf2f(hi));
      }
      // pooled g (+bias, f32) -> LDS for the block-wide g2 transform
      int mi = sub >> 2;                    // 0..15 local pooled point
      float* al = comb + mi*33;             // padded row (bank-free)
      #pragma unroll
      for (int o = 0; o < 32; ++o) al[o] = ag[o] + b_g[o];
    }
  }
  __syncthreads();

  // ---- g2 transform: 16 m-points x 64 co per block, all 256 threads.
  // thread -> (mi = tid&15, cow = tid>>4); 4 co's per thread (cow + j*16).
  {
    int mi  = tid & 15;
    int cow = tid >> 4;                     // 0..15
    int bb  = blockIdx.x >> 6;              // batch (64 blocks/batch)
    int mb  = (blockIdx.x & 63) * 16;       // m base
    float av[32];
    #pragma unroll
    for (int c = 0; c < 32; ++c) av[c] = comb[mi*33 + c];
    #pragma unroll
    for (int j = 0; j < 4; ++j) {
      int co = cow + j*16;
      const float* wl = wlds + co*33;
      float a = 0.f;
      #pragma unroll
      for (int c = 0; c < 32; ++c) a += av[c] * wl[c];
      g2_t[((size_t)bb*64 + co)*M_ + mb + mi] = f2bf(a);
    }
  }
}

// ---------------------------------------------------------------------------
// K2: MFMA flash attention (no-max softmax) with w_last pre-folded into g2.
// Wave split back to R1's (4 row-groups x 2 key-halves).  4 phases of 256
// keys (g2 is 64-wide: 32 KB/phase, XOR-swizzled byte^=(row&7)<<4 so the
// stride-512B co-rows read conflict-free at 2 blocks/CU).  PV accumulates
// the 64-wide conv numerator; epilogue is 16 trivial ops/thread (the old
// 512-FMA/thread GEMV is gone).
// ---------------------------------------------------------------------------
__global__ __launch_bounds__(512, 4)
void k_attn(const float* __restrict__ x,
            const unsigned short* __restrict__ delta_s,
            const unsigned short* __restrict__ phi_s,
            const unsigned short* __restrict__ g2_t,
            const float* __restrict__ b_last,
            const float* __restrict__ gamma,
            float* __restrict__ out) {
  __shared__ __align__(16) unsigned char lds_raw[40960];
  unsigned short* phi_lds = (unsigned short*)lds_raw;      // 256*16*2 = 8192 B
  unsigned char*  g2_lds  = lds_raw + 8192;                // 64*256*2 = 32768 B (swz)
  float* cmb = (float*)lds_raw;                            // 128*66*4 = 33792 B (reuse)

  int tid  = threadIdx.x;
  int lane = tid & 63;
  int wv   = tid >> 6;             // 0..7
  int rg   = wv & 3;               // row-group: rows rg*32 .. rg*32+31
  int kh   = wv >> 2;              // key half within phase (128 keys)
  int r    = lane & 15;
  int q    = lane >> 4;
  int bx = blockIdx.x;             // 0..511
  int b  = bx >> 5;
  int n0 = (bx & 31) * 128;

  // ---- df fragments straight from global (coalesced 16B/lane, L1-shared)
  bf16x8 df[2];
  {
    const unsigned short* dp =
        delta_s + ((size_t)b*HW_ + n0 + rg*32 + r)*16 + (q & 1)*8;
    df[0] = *(const bf16x8*)(dp);
    df[1] = *(const bf16x8*)(dp + 16*16);   // +16 rows
  }

  int phi_off = (q >> 1) * 8;               // [ph ph pl pl] across k
  int key0 = (r >> 2)*8 + (r & 3);          // perm: S-tile C-layout == PV A-frag
  int key1 = key0 + 4;

  bf16x8 ones;
  #pragma unroll
  for (int i = 0; i < 8; ++i) ones[i] = (short)0x3F80;  // bf16 1.0

  f32x4 acc[2][4];                 // [tile][co-group 0..3]
  f32x4 den[2];
  f32x4 zero = {0,0,0,0};
  #pragma unroll
  for (int t = 0; t < 2; ++t) {
    #pragma unroll
    for (int cg = 0; cg < 4; ++cg) acc[t][cg] = zero;
    den[t] = zero;
  }

  for (int p = 0; p < 4; ++p) {
    if (p) __syncthreads();                 // everyone done reading prev phase
    // ---- stage phi quarter: 512 16B units (1/thread)
    {
      const uint4* psrc = (const uint4*)(phi_s + ((size_t)b*M_ + p*256)*16);
      ((uint4*)phi_lds)[tid] = psrc[tid];
      // ---- stage g2 quarter: 2048 16B units, XOR-swizzled rows
      #pragma unroll
      for (int i = 0; i < 4; ++i) {
        int u = tid + i*512;
        int co = u >> 5, pos = u & 31;
        unsigned byte = (unsigned)(co*512 + pos*16) ^ (unsigned)((co & 7) << 4);
        *(uint4*)(g2_lds + byte) =
            *(const uint4*)(g2_t + ((size_t)b*64 + co)*M_ + p*256 + pos*8);
      }
    }
    __syncthreads();

    // ---- K-loop on LDS only (no barriers inside): 4 steps of 32 keys
    #pragma unroll 2
    for (int kc = 0; kc < 128; kc += 32) {
      int kl = kh*128 + kc;        // phase-local key base
      bf16x8 aphi0 = *(const bf16x8*)(phi_lds + (size_t)(kl + key0)*16 + phi_off);
      bf16x8 aphi1 = *(const bf16x8*)(phi_lds + (size_t)(kl + key1)*16 + phi_off);
      bf16x8 bg[4];
      #pragma unroll
      for (int cg = 0; cg < 4; ++cg) {
        unsigned byte = (unsigned)((cg*16 + r)*512 + kl*2 + q*16)
                      ^ (unsigned)((r & 7) << 4);
        bg[cg] = *(const bf16x8*)(g2_lds + byte);
      }

      #pragma unroll
      for (int t = 0; t < 2; ++t) {
        f32x4 s0 = MFMA_BF16(aphi0, df[t], zero, 0, 0, 0);
        f32x4 s1 = MFMA_BF16(aphi1, df[t], zero, 0, 0, 0);
        union { bf16x8 v; __hip_bfloat162 h[4]; } e;
        e.h[0] = __float22bfloat162_rn(make_float2(__builtin_amdgcn_exp2f(s0[0]),
                                                   __builtin_amdgcn_exp2f(s0[1])));
        e.h[1] = __float22bfloat162_rn(make_float2(__builtin_amdgcn_exp2f(s0[2]),
                                                   __builtin_amdgcn_exp2f(s0[3])));
        e.h[2] = __float22bfloat162_rn(make_float2(__builtin_amdgcn_exp2f(s1[0]),
                                                   __builtin_amdgcn_exp2f(s1[1])));
        e.h[3] = __float22bfloat162_rn(make_float2(__builtin_amdgcn_exp2f(s1[2]),
                                                   __builtin_amdgcn_exp2f(s1[3])));
        #pragma unroll
        for (int cg = 0; cg < 4; ++cg)
          acc[t][cg] = MFMA_BF16(e.v, bg[cg], acc[t][cg], 0, 0, 0);
        den[t] = MFMA_BF16(e.v, ones, den[t], 0, 0, 0);
      }
    }
  }

  // ---- combine the two key-halves (cmb reuses staging LDS)
  __syncthreads();                          // all waves done reading g2/phi LDS
  if (kh == 1) {
    #pragma unroll
    for (int t = 0; t < 2; ++t) {
      #pragma unroll
      for (int reg = 0; reg < 4; ++reg) {
        int row = rg*32 + t*16 + q*4 + reg;
        #pragma unroll
        for (int cg = 0; cg < 4; ++cg)
          cmb[row*66 + cg*16 + r] = acc[t][cg][reg];
        if (r == 0) cmb[row*66 + 64] = den[t][reg];
      }
    }
  }
  __syncthreads();
  if (kh == 0) {
    #pragma unroll
    for (int t = 0; t < 2; ++t) {
      #pragma unroll
      for (int reg = 0; reg < 4; ++reg) {
        int row = rg*32 + t*16 + q*4 + reg;
        float dn = den[t][reg] + cmb[row*66 + 64];
        float iv = __builtin_amdgcn_rcpf(dn);
        #pragma unroll
        for (int cg = 0; cg < 4; ++cg) {
          float o = acc[t][cg][reg] + cmb[row*66 + cg*16 + r];
          cmb[row*66 + cg*16 + r] = o * iv;   // in-place: same slot it read
        }
      }
    }
  }
  __syncthreads();

  // ---- epilogue: out[b,co,n0+rr] = gamma*(cmb[rr][co] + b_last[co]) + x
  int rr  = tid & 127;
  int wqu = __builtin_amdgcn_readfirstlane(tid >> 7);  // 0..3, uniform
  float gm = gamma[0];
  #pragma unroll
  for (int i = 0; i < 16; ++i) {
    int co = wqu*16 + i;                     // uniform -> s_load bias
    float val = cmb[rr*66 + co];
    size_t oi = ((size_t)b*C_ + co)*HW_ + (size_t)(n0 + rr);
    out[oi] = gm * (val + b_last[co]) + x[oi];
  }
}

// ---------------------------------------------------------------------------
extern "C" void kernel_launch(void* const* d_in, const int* in_sizes, int n_in,
                              void* d_out, int out_size, void* d_ws, size_t ws_size,
                              hipStream_t stream) {
  const float* x       = (const float*)d_in[0];
  const float* w_delta = (const float*)d_in[1];
  const float* b_delta = (const float*)d_in[2];
  const float* w_phi   = (const float*)d_in[3];
  const float* b_phi   = (const float*)d_in[4];
  const float* w_g     = (const float*)d_in[5];
  const float* b_g     = (const float*)d_in[6];
  const float* w_last  = (const float*)d_in[7];
  const float* b_last  = (const float*)d_in[8];
  const float* gamma   = (const float*)d_in[9];
  float* out = (float*)d_out;

  unsigned short* ws = (unsigned short*)d_ws;
  unsigned short* phi_s   = ws;                                        // 0.5 MB
  unsigned short* g2_t    = ws + (size_t)B_*M_*16;                     // 2 MB
  unsigned short* delta_s = ws + (size_t)B_*M_*16 + (size_t)B_*64*M_;  // 2 MB

  hipLaunchKernelGGL(k_pre, dim3(1024), dim3(256), 0, stream,
                     x, w_delta, b_delta, w_phi, b_phi, w_g, b_g, w_last,
                     delta_s, phi_s, g2_t);
  hipLaunchKernelGGL(k_attn, dim3(512), dim3(512), 0, stream,
                     x, delta_s, phi_s, g2_t, b_last, gamma, out);
}

// Round 7
// 114.083 us; speedup vs baseline: 1.0207x; 1.0207x over previous
//
#include <hip/hip_runtime.h>
#include <hip/hip_bf16.h>
#include <math.h>

typedef __attribute__((ext_vector_type(8))) short bf16x8;
typedef __attribute__((ext_vector_type(4))) float f32x4;

#define B_   16
#define C_   64
#define C1_  8
#define C2_  32
#define HW_  4096
#define M_   1024
#define LOG2E 1.4426950408889634f
#define MFMA_BF16 __builtin_amdgcn_mfma_f32_16x16x32_bf16

__device__ __forceinline__ unsigned short f2bf(float f) {
  union { float f; unsigned u; } v; v.f = f;
  unsigned r = (v.u + 0x7fffu + ((v.u >> 16) & 1u)) >> 16;
  return (unsigned short)r;
}
__device__ __forceinline__ float bf2f(unsigned short h) {
  union { unsigned u; float f; } v; v.u = ((unsigned)h) << 16;
  return v.f;
}

// ---------------------------------------------------------------------------
// K1: delta + phi + g (exact R1 checkpoint, 113.2 us verified).
//   delta_s[b][n][16] : [dh(8) dl(8)] hi/lo split, LOG2E prefolded
//   phi_s[b][m][16]   : [ph(8) pl(8)] hi/lo split
//   g_t  [b][c2][m]   : bf16 (transposed for PV B-frag reads)
// ---------------------------------------------------------------------------
__global__ __launch_bounds__(256, 4)
void k_pre(const float* __restrict__ x,
           const float* __restrict__ w_delta, const float* __restrict__ b_delta,
           const float* __restrict__ w_phi, const float* __restrict__ b_phi,
           const float* __restrict__ w_g,   const float* __restrict__ b_g,
           unsigned short* __restrict__ delta_s,
           unsigned short* __restrict__ phi_s,
           unsigned short* __restrict__ g_t) {
  __shared__ float comb[2*64*49];
  int tid = threadIdx.x;

  int qt  = tid >> 6;              // channel quarter == wave index
  int sub = tid & 63;
  int id  = blockIdx.x * 64 + sub; // pixel id 0..65535
  int pix = id & 3;                // 2x2 corner (lane bits 0..1)
  int pm  = id >> 2;
  int b = pm >> 10;
  int m = pm & 1023;
  int py = 2*(m >> 5) + (pix >> 1);
  int px = 2*(m & 31) + (pix & 1);
  int n = py * 64 + px;

  int c0 = __builtin_amdgcn_readfirstlane(qt << 4);

  const float* xp = x + ((size_t)b*C_ + c0)*HW_ + n;
  float xv[16];
  #pragma unroll
  for (int i = 0; i < 16; ++i) xv[i] = xp[(size_t)i * HW_];

  float ad[8], ap[8], ag[32];
  #pragma unroll
  for (int o = 0; o < 8; ++o) {
    const float* wd = w_delta + o*C_ + c0;   // uniform -> s_load
    float a = 0.f;
    #pragma unroll
    for (int i = 0; i < 16; ++i) a += xv[i]*wd[i];
    ad[o] = a;
  }
  #pragma unroll
  for (int o = 0; o < 8; ++o) {
    const float* wp = w_phi + o*C_ + c0;     // uniform -> s_load
    float a = 0.f;
    #pragma unroll
    for (int i = 0; i < 16; ++i) a += xv[i]*wp[i];
    ap[o] = a;
  }
  #pragma unroll
  for (int o = 0; o < 32; ++o) {
    const float* wg = w_g + o*C_ + c0;       // uniform -> s_load
    float a = 0.f;
    #pragma unroll
    for (int i = 0; i < 16; ++i) a += xv[i]*wg[i];
    ag[o] = a;
  }

  if (qt == 1 || qt == 3) {
    float* cb = comb + (((qt >> 1)*64) + sub)*49;
    #pragma unroll
    for (int o = 0; o < 8; ++o) cb[o] = ad[o];
    #pragma unroll
    for (int o = 0; o < 8; ++o) cb[8+o] = ap[o];
    #pragma unroll
    for (int o = 0; o < 32; ++o) cb[16+o] = ag[o];
  }
  __syncthreads();
  if (qt == 0 || qt == 2) {
    const float* cb = comb + (((qt >> 1)*64) + sub)*49;
    #pragma unroll
    for (int o = 0; o < 8; ++o) ad[o] += cb[o];
    #pragma unroll
    for (int o = 0; o < 8; ++o) ap[o] += cb[8+o];
    #pragma unroll
    for (int o = 0; o < 32; ++o) ag[o] += cb[16+o];
  }
  __syncthreads();
  if (qt == 2) {
    float* cb = comb + sub*49;
    #pragma unroll
    for (int o = 0; o < 8; ++o) cb[o] = ad[o];
    #pragma unroll
    for (int o = 0; o < 8; ++o) cb[8+o] = ap[o];
    #pragma unroll
    for (int o = 0; o < 32; ++o) cb[16+o] = ag[o];
  }
  __syncthreads();
  if (qt == 0) {
    const float* cb = comb + sub*49;
    #pragma unroll
    for (int o = 0; o < 8; ++o) ad[o] += cb[o];
    #pragma unroll
    for (int o = 0; o < 8; ++o) ap[o] += cb[8+o];
    #pragma unroll
    for (int o = 0; o < 32; ++o) ag[o] += cb[16+o];

    // ---- delta: full-resolution, every lane writes its pixel (no pooling)
    {
      union { unsigned short s[8]; uint4 v; } dh, dl;
      #pragma unroll
      for (int o = 0; o < 8; ++o) {
        float v = (ad[o] + b_delta[o]) * LOG2E;
        unsigned short hi = f2bf(v);
        dh.s[o] = hi;
        dl.s[o] = f2bf(v - bf2f(hi));
      }
      uint4* dp = (uint4*)(delta_s + ((size_t)b*HW_ + n)*16);
      dp[0] = dh.v;
      dp[1] = dl.v;
    }

    // ---- phi/g: 2x2 shuffle max-pool, then (sub&3)==0 writes
    #pragma unroll
    for (int o = 0; o < 8; ++o) {
      float v = ap[o];
      v = fmaxf(v, __shfl_xor(v, 1));
      v = fmaxf(v, __shfl_xor(v, 2));
      ap[o] = v;
    }
    #pragma unroll
    for (int o = 0; o < 32; ++o) {
      float v = ag[o];
      v = fmaxf(v, __shfl_xor(v, 1));
      v = fmaxf(v, __shfl_xor(v, 2));
      ag[o] = v;
    }

    if ((sub & 3) == 0) {
      #pragma unroll
      for (int cp = 0; cp < 8; ++cp) {
        int f = cp*16 + b;
        float v = ap[cp] + b_phi[cp];
        unsigned short hi = f2bf(v);
        unsigned short* pr = phi_s + ((size_t)(f >> 3)*M_ + m)*16;
        pr[f & 7]       = hi;
        pr[8 + (f & 7)] = f2bf(v - bf2f(hi));
      }
      #pragma unroll
      for (int o = 0; o < 32; ++o)
        g_t[((size_t)b*C2_ + o)*M_ + m] = f2bf(ag[o] + b_g[o]);
    }
  }
}

// ---------------------------------------------------------------------------
// K2: MFMA flash attention (no-max softmax) + fused last conv + residual.
// Exact R1 structure (113.2 us verified) + ONE change this round:
// T5 s_setprio(1)/(0) around the MFMA+exp compute cluster in the K-loop.
// The K-loop has no internal barriers, so the 8 waves drift out of phase —
// priority lets compute-cluster waves win SIMD issue arbitration over
// waves that are issuing ds_reads (m191-style role diversity).
// ---------------------------------------------------------------------------
__global__ __launch_bounds__(512, 4)
void k_attn(const float* __restrict__ x,
            const unsigned short* __restrict__ delta_s,
            const unsigned short* __restrict__ phi_s,
            const unsigned short* __restrict__ g_t,
            const float* __restrict__ w_last,
            const float* __restrict__ b_last,
            const float* __restrict__ gamma,
            float* __restrict__ out) {
  __shared__ __align__(16) unsigned char lds_raw[50176];
  unsigned short* phi_lds = (unsigned short*)lds_raw;          // 512*16*2  = 16384 B
  unsigned short* g_lds   = (unsigned short*)(lds_raw + 16384);// 32*520*2  = 33280 B
  float* o_sh = (float*)lds_raw;                               // 128*33*4  = 16896 B (reuse)
  float* cmb  = (float*)(lds_raw + 16896);                     // 128*34*4  = 17408 B (reuse)

  int tid  = threadIdx.x;
  int lane = tid & 63;
  int wv   = tid >> 6;             // 0..7
  int rg   = wv & 3;               // row-group: rows rg*32 .. rg*32+31
  int kh   = wv >> 2;              // key half within phase (256 keys)
  int r    = lane & 15;
  int q    = lane >> 4;
  int bx = blockIdx.x;             // 0..511
  int b  = bx >> 5;
  int n0 = (bx & 31) * 128;

  // ---- df fragments straight from global (coalesced 16B/lane, L1-shared)
  bf16x8 df[2];
  {
    const unsigned short* dp =
        delta_s + ((size_t)b*HW_ + n0 + rg*32 + r)*16 + (q & 1)*8;
    df[0] = *(const bf16x8*)(dp);
    df[1] = *(const bf16x8*)(dp + 16*16);   // +16 rows
  }

  int phi_off = (q >> 1) * 8;               // [ph ph pl pl] across k
  int key0 = (r >> 2)*8 + (r & 3);          // perm: S-tile C-layout == PV A-frag
  int key1 = key0 + 4;

  bf16x8 ones;
  #pragma unroll
  for (int i = 0; i < 8; ++i) ones[i] = (short)0x3F80;  // bf16 1.0

  f32x4 acc[2][2];                 // [tile][c-half]
  f32x4 den[2];
  f32x4 zero = {0,0,0,0};
  #pragma unroll
  for (int t = 0; t < 2; ++t) { acc[t][0] = zero; acc[t][1] = zero; den[t] = zero; }

  for (int p = 0; p < 2; ++p) {
    if (p) __syncthreads();                 // everyone done reading phase 0
    // ---- stage phi half: 1024 16B units, straight copy
    {
      const uint4* psrc = (const uint4*)(phi_s + ((size_t)b*M_ + p*512)*16);
      uint4* pdst = (uint4*)phi_lds;
      #pragma unroll
      for (int u = 0; u < 2; ++u) pdst[tid + u*512] = psrc[tid + u*512];
      // ---- stage g half: 2048 16B units into padded rows
      #pragma unroll
      for (int u = 0; u < 4; ++u) {
        int uu = tid + u*512;
        int c2 = uu >> 6, pos = uu & 63;
        *(uint4*)(g_lds + c2*520 + pos*8) =
            *(const uint4*)(g_t + ((size_t)b*C2_ + c2)*M_ + p*512 + pos*8);
      }
    }
    __syncthreads();

    // ---- K-loop on LDS only (no barriers inside)
    #pragma unroll 2
    for (int kc = 0; kc < 256; kc += 32) {
      int kl = kh*256 + kc;        // phase-local key base
      bf16x8 aphi0 = *(const bf16x8*)(phi_lds + (size_t)(kl + key0)*16 + phi_off);
      bf16x8 aphi1 = *(const bf16x8*)(phi_lds + (size_t)(kl + key1)*16 + phi_off);
      bf16x8 bg0   = *(const bf16x8*)(g_lds + r*520        + kl + q*8);
      bf16x8 bg1   = *(const bf16x8*)(g_lds + (16 + r)*520 + kl + q*8);

      __builtin_amdgcn_s_setprio(1);        // favor compute-cluster waves
      #pragma unroll
      for (int t = 0; t < 2; ++t) {
        f32x4 s0 = MFMA_BF16(aphi0, df[t], zero, 0, 0, 0);
        f32x4 s1 = MFMA_BF16(aphi1, df[t], zero, 0, 0, 0);
        union { bf16x8 v; __hip_bfloat162 h[4]; } e;
        e.h[0] = __float22bfloat162_rn(make_float2(__builtin_amdgcn_exp2f(s0[0]),
                                                   __builtin_amdgcn_exp2f(s0[1])));
        e.h[1] = __float22bfloat162_rn(make_float2(__builtin_amdgcn_exp2f(s0[2]),
                                                   __builtin_amdgcn_exp2f(s0[3])));
        e.h[2] = __float22bfloat162_rn(make_float2(__builtin_amdgcn_exp2f(s1[0]),
                                                   __builtin_amdgcn_exp2f(s1[1])));
        e.h[3] = __float22bfloat162_rn(make_float2(__builtin_amdgcn_exp2f(s1[2]),
                                                   __builtin_amdgcn_exp2f(s1[3])));
        acc[t][0] = MFMA_BF16(e.v, bg0, acc[t][0], 0, 0, 0);
        acc[t][1] = MFMA_BF16(e.v, bg1, acc[t][1], 0, 0, 0);
        den[t]    = MFMA_BF16(e.v, ones, den[t], 0, 0, 0);
      }
      __builtin_amdgcn_s_setprio(0);
    }
  }

  // ---- combine the two key-halves (cmb reuses staging LDS)
  __syncthreads();                          // all waves done reading g/phi LDS
  if (kh == 1) {
    #pragma unroll
    for (int t = 0; t < 2; ++t) {
      #pragma unroll
      for (int reg = 0; reg < 4; ++reg) {
        int row = rg*32 + t*16 + q*4 + reg;
        cmb[row*34 + r]      = acc[t][0][reg];
        cmb[row*34 + 16 + r] = acc[t][1][reg];
        if (r == 0) cmb[row*34 + 32] = den[t][reg];
      }
    }
  }
  __syncthreads();
  if (kh == 0) {
    #pragma unroll
    for (int t = 0; t < 2; ++t) {
      #pragma unroll
      for (int reg = 0; reg < 4; ++reg) {
        int row = rg*32 + t*16 + q*4 + reg;
        float o0 = acc[t][0][reg] + cmb[row*34 + r];
        float o1 = acc[t][1][reg] + cmb[row*34 + 16 + r];
        float dn = den[t][reg]    + cmb[row*34 + 32];
        float iv = __builtin_amdgcn_rcpf(dn);
        o_sh[row*33 + r]      = o0 * iv;
        o_sh[row*33 + 16 + r] = o1 * iv;
      }
    }
  }
  __syncthreads();

  // ---- epilogue: out[b,co,n0+rr] = gamma*(w_last[co,:].O[rr,:]+b_last[co])+x
  int rr  = tid & 127;
  int wqu = __builtin_amdgcn_readfirstlane(tid >> 7);  // 0..3, uniform
  float o_reg[32];
  #pragma unroll
  for (int c = 0; c < 32; ++c) o_reg[c] = o_sh[rr*33 + c];
  float gm = gamma[0];
  for (int i = 0; i < 16; ++i) {
    int co = wqu*16 + i;                     // uniform -> s_load weights
    const float* wl = w_last + co*32;
    float a = b_last[co];
    #pragma unroll
    for (int c = 0; c < 32; ++c) a += wl[c] * o_reg[c];
    size_t oi = ((size_t)b*C_ + co)*HW_ + (size_t)(n0 + rr);
    out[oi] = gm * a + x[oi];
  }
}

// ---------------------------------------------------------------------------
extern "C" void kernel_launch(void* const* d_in, const int* in_sizes, int n_in,
                              void* d_out, int out_size, void* d_ws, size_t ws_size,
                              hipStream_t stream) {
  const float* x       = (const float*)d_in[0];
  const float* w_delta = (const float*)d_in[1];
  const float* b_delta = (const float*)d_in[2];
  const float* w_phi   = (const float*)d_in[3];
  const float* b_phi   = (const float*)d_in[4];
  const float* w_g     = (const float*)d_in[5];
  const float* b_g     = (const float*)d_in[6];
  const float* w_last  = (const float*)d_in[7];
  const float* b_last  = (const float*)d_in[8];
  const float* gamma   = (const float*)d_in[9];
  float* out = (float*)d_out;

  unsigned short* ws = (unsigned short*)d_ws;
  unsigned short* phi_s   = ws;                                        // 0.5 MB
  unsigned short* g_t     = ws + (size_t)B_*M_*16;                     // 1 MB
  unsigned short* delta_s = ws + (size_t)B_*M_*16 + (size_t)B_*C2_*M_; // 2 MB

  hipLaunchKernelGGL(k_pre, dim3(1024), dim3(256), 0, stream,
                     x, w_delta, b_delta, w_phi, b_phi, w_g, b_g,
                     delta_s, phi_s, g_t);
  hipLaunchKernelGGL(k_attn, dim3(512), dim3(512), 0, stream,
                     x, delta_s, phi_s, g_t, w_last, b_last, gamma, out);
}

// Round 8
// 112.602 us; speedup vs baseline: 1.0341x; 1.0131x over previous
//
#include <hip/hip_runtime.h>
#include <hip/hip_bf16.h>
#include <math.h>

typedef __attribute__((ext_vector_type(8))) short bf16x8;
typedef __attribute__((ext_vector_type(4))) float f32x4;

#define B_   16
#define C_   64
#define C1_  8
#define C2_  32
#define HW_  4096
#define M_   1024
#define LOG2E 1.4426950408889634f
#define MFMA_BF16 __builtin_amdgcn_mfma_f32_16x16x32_bf16

__device__ __forceinline__ unsigned short f2bf(float f) {
  union { float f; unsigned u; } v; v.f = f;
  unsigned r = (v.u + 0x7fffu + ((v.u >> 16) & 1u)) >> 16;
  return (unsigned short)r;
}
__device__ __forceinline__ float bf2f(unsigned short h) {
  union { unsigned u; float f; } v; v.u = ((unsigned)h) << 16;
  return v.f;
}

// ---------------------------------------------------------------------------
// K1: delta + phi + g (exact R1 checkpoint, 113.2 us verified).
//   delta_s[b][n][16] : [dh(8) dl(8)] hi/lo split, LOG2E prefolded
//   phi_s[b][m][16]   : [ph(8) pl(8)] hi/lo split
//   g_t  [b][c2][m]   : bf16 (transposed for PV B-frag reads)
// ---------------------------------------------------------------------------
__global__ __launch_bounds__(256, 4)
void k_pre(const float* __restrict__ x,
           const float* __restrict__ w_delta, const float* __restrict__ b_delta,
           const float* __restrict__ w_phi, const float* __restrict__ b_phi,
           const float* __restrict__ w_g,   const float* __restrict__ b_g,
           unsigned short* __restrict__ delta_s,
           unsigned short* __restrict__ phi_s,
           unsigned short* __restrict__ g_t) {
  __shared__ float comb[2*64*49];
  int tid = threadIdx.x;

  int qt  = tid >> 6;              // channel quarter == wave index
  int sub = tid & 63;
  int id  = blockIdx.x * 64 + sub; // pixel id 0..65535
  int pix = id & 3;                // 2x2 corner (lane bits 0..1)
  int pm  = id >> 2;
  int b = pm >> 10;
  int m = pm & 1023;
  int py = 2*(m >> 5) + (pix >> 1);
  int px = 2*(m & 31) + (pix & 1);
  int n = py * 64 + px;

  int c0 = __builtin_amdgcn_readfirstlane(qt << 4);

  const float* xp = x + ((size_t)b*C_ + c0)*HW_ + n;
  float xv[16];
  #pragma unroll
  for (int i = 0; i < 16; ++i) xv[i] = xp[(size_t)i * HW_];

  float ad[8], ap[8], ag[32];
  #pragma unroll
  for (int o = 0; o < 8; ++o) {
    const float* wd = w_delta + o*C_ + c0;   // uniform -> s_load
    float a = 0.f;
    #pragma unroll
    for (int i = 0; i < 16; ++i) a += xv[i]*wd[i];
    ad[o] = a;
  }
  #pragma unroll
  for (int o = 0; o < 8; ++o) {
    const float* wp = w_phi + o*C_ + c0;     // uniform -> s_load
    float a = 0.f;
    #pragma unroll
    for (int i = 0; i < 16; ++i) a += xv[i]*wp[i];
    ap[o] = a;
  }
  #pragma unroll
  for (int o = 0; o < 32; ++o) {
    const float* wg = w_g + o*C_ + c0;       // uniform -> s_load
    float a = 0.f;
    #pragma unroll
    for (int i = 0; i < 16; ++i) a += xv[i]*wg[i];
    ag[o] = a;
  }

  if (qt == 1 || qt == 3) {
    float* cb = comb + (((qt >> 1)*64) + sub)*49;
    #pragma unroll
    for (int o = 0; o < 8; ++o) cb[o] = ad[o];
    #pragma unroll
    for (int o = 0; o < 8; ++o) cb[8+o] = ap[o];
    #pragma unroll
    for (int o = 0; o < 32; ++o) cb[16+o] = ag[o];
  }
  __syncthreads();
  if (qt == 0 || qt == 2) {
    const float* cb = comb + (((qt >> 1)*64) + sub)*49;
    #pragma unroll
    for (int o = 0; o < 8; ++o) ad[o] += cb[o];
    #pragma unroll
    for (int o = 0; o < 8; ++o) ap[o] += cb[8+o];
    #pragma unroll
    for (int o = 0; o < 32; ++o) ag[o] += cb[16+o];
  }
  __syncthreads();
  if (qt == 2) {
    float* cb = comb + sub*49;
    #pragma unroll
    for (int o = 0; o < 8; ++o) cb[o] = ad[o];
    #pragma unroll
    for (int o = 0; o < 8; ++o) cb[8+o] = ap[o];
    #pragma unroll
    for (int o = 0; o < 32; ++o) cb[16+o] = ag[o];
  }
  __syncthreads();
  if (qt == 0) {
    const float* cb = comb + sub*49;
    #pragma unroll
    for (int o = 0; o < 8; ++o) ad[o] += cb[o];
    #pragma unroll
    for (int o = 0; o < 8; ++o) ap[o] += cb[8+o];
    #pragma unroll
    for (int o = 0; o < 32; ++o) ag[o] += cb[16+o];

    // ---- delta: full-resolution, every lane writes its pixel (no pooling)
    {
      union { unsigned short s[8]; uint4 v; } dh, dl;
      #pragma unroll
      for (int o = 0; o < 8; ++o) {
        float v = (ad[o] + b_delta[o]) * LOG2E;
        unsigned short hi = f2bf(v);
        dh.s[o] = hi;
        dl.s[o] = f2bf(v - bf2f(hi));
      }
      uint4* dp = (uint4*)(delta_s + ((size_t)b*HW_ + n)*16);
      dp[0] = dh.v;
      dp[1] = dl.v;
    }

    // ---- phi/g: 2x2 shuffle max-pool, then (sub&3)==0 writes
    #pragma unroll
    for (int o = 0; o < 8; ++o) {
      float v = ap[o];
      v = fmaxf(v, __shfl_xor(v, 1));
      v = fmaxf(v, __shfl_xor(v, 2));
      ap[o] = v;
    }
    #pragma unroll
    for (int o = 0; o < 32; ++o) {
      float v = ag[o];
      v = fmaxf(v, __shfl_xor(v, 1));
      v = fmaxf(v, __shfl_xor(v, 2));
      ag[o] = v;
    }

    if ((sub & 3) == 0) {
      #pragma unroll
      for (int cp = 0; cp < 8; ++cp) {
        int f = cp*16 + b;
        float v = ap[cp] + b_phi[cp];
        unsigned short hi = f2bf(v);
        unsigned short* pr = phi_s + ((size_t)(f >> 3)*M_ + m)*16;
        pr[f & 7]       = hi;
        pr[8 + (f & 7)] = f2bf(v - bf2f(hi));
      }
      #pragma unroll
      for (int o = 0; o < 32; ++o)
        g_t[((size_t)b*C2_ + o)*M_ + m] = f2bf(ag[o] + b_g[o]);
    }
  }
}

// ---------------------------------------------------------------------------
// K2: MFMA flash attention (no-max softmax) + fused last conv + residual.
// Exact R1 checkpoint (113.2 us verified): setprio removed (R7 showed it
// null-to-negative on this barrier-phase-locked structure, matching m190).
// Block = 512 thr (8 waves = 4 row-groups x 2 key-halves), 128 Q-rows,
// 512 blocks. phi+g staged through LDS in two key-phases; K-loop reads
// only LDS.
// ---------------------------------------------------------------------------
__global__ __launch_bounds__(512, 4)
void k_attn(const float* __restrict__ x,
            const unsigned short* __restrict__ delta_s,
            const unsigned short* __restrict__ phi_s,
            const unsigned short* __restrict__ g_t,
            const float* __restrict__ w_last,
            const float* __restrict__ b_last,
            const float* __restrict__ gamma,
            float* __restrict__ out) {
  __shared__ __align__(16) unsigned char lds_raw[50176];
  unsigned short* phi_lds = (unsigned short*)lds_raw;          // 512*16*2  = 16384 B
  unsigned short* g_lds   = (unsigned short*)(lds_raw + 16384);// 32*520*2  = 33280 B
  float* o_sh = (float*)lds_raw;                               // 128*33*4  = 16896 B (reuse)
  float* cmb  = (float*)(lds_raw + 16896);                     // 128*34*4  = 17408 B (reuse)

  int tid  = threadIdx.x;
  int lane = tid & 63;
  int wv   = tid >> 6;             // 0..7
  int rg   = wv & 3;               // row-group: rows rg*32 .. rg*32+31
  int kh   = wv >> 2;              // key half within phase (256 keys)
  int r    = lane & 15;
  int q    = lane >> 4;
  int bx = blockIdx.x;             // 0..511
  int b  = bx >> 5;
  int n0 = (bx & 31) * 128;

  // ---- df fragments straight from global (coalesced 16B/lane, L1-shared)
  bf16x8 df[2];
  {
    const unsigned short* dp =
        delta_s + ((size_t)b*HW_ + n0 + rg*32 + r)*16 + (q & 1)*8;
    df[0] = *(const bf16x8*)(dp);
    df[1] = *(const bf16x8*)(dp + 16*16);   // +16 rows
  }

  int phi_off = (q >> 1) * 8;               // [ph ph pl pl] across k
  int key0 = (r >> 2)*8 + (r & 3);          // perm: S-tile C-layout == PV A-frag
  int key1 = key0 + 4;

  bf16x8 ones;
  #pragma unroll
  for (int i = 0; i < 8; ++i) ones[i] = (short)0x3F80;  // bf16 1.0

  f32x4 acc[2][2];                 // [tile][c-half]
  f32x4 den[2];
  f32x4 zero = {0,0,0,0};
  #pragma unroll
  for (int t = 0; t < 2; ++t) { acc[t][0] = zero; acc[t][1] = zero; den[t] = zero; }

  for (int p = 0; p < 2; ++p) {
    if (p) __syncthreads();                 // everyone done reading phase 0
    // ---- stage phi half: 1024 16B units, straight copy
    {
      const uint4* psrc = (const uint4*)(phi_s + ((size_t)b*M_ + p*512)*16);
      uint4* pdst = (uint4*)phi_lds;
      #pragma unroll
      for (int u = 0; u < 2; ++u) pdst[tid + u*512] = psrc[tid + u*512];
      // ---- stage g half: 2048 16B units into padded rows
      #pragma unroll
      for (int u = 0; u < 4; ++u) {
        int uu = tid + u*512;
        int c2 = uu >> 6, pos = uu & 63;
        *(uint4*)(g_lds + c2*520 + pos*8) =
            *(const uint4*)(g_t + ((size_t)b*C2_ + c2)*M_ + p*512 + pos*8);
      }
    }
    __syncthreads();

    // ---- K-loop on LDS only (no barriers inside)
    #pragma unroll 2
    for (int kc = 0; kc < 256; kc += 32) {
      int kl = kh*256 + kc;        // phase-local key base
      bf16x8 aphi0 = *(const bf16x8*)(phi_lds + (size_t)(kl + key0)*16 + phi_off);
      bf16x8 aphi1 = *(const bf16x8*)(phi_lds + (size_t)(kl + key1)*16 + phi_off);
      bf16x8 bg0   = *(const bf16x8*)(g_lds + r*520        + kl + q*8);
      bf16x8 bg1   = *(const bf16x8*)(g_lds + (16 + r)*520 + kl + q*8);

      #pragma unroll
      for (int t = 0; t < 2; ++t) {
        f32x4 s0 = MFMA_BF16(aphi0, df[t], zero, 0, 0, 0);
        f32x4 s1 = MFMA_BF16(aphi1, df[t], zero, 0, 0, 0);
        union { bf16x8 v; __hip_bfloat162 h[4]; } e;
        e.h[0] = __float22bfloat162_rn(make_float2(__builtin_amdgcn_exp2f(s0[0]),
                                                   __builtin_amdgcn_exp2f(s0[1])));
        e.h[1] = __float22bfloat162_rn(make_float2(__builtin_amdgcn_exp2f(s0[2]),
                                                   __builtin_amdgcn_exp2f(s0[3])));
        e.h[2] = __float22bfloat162_rn(make_float2(__builtin_amdgcn_exp2f(s1[0]),
                                                   __builtin_amdgcn_exp2f(s1[1])));
        e.h[3] = __float22bfloat162_rn(make_float2(__builtin_amdgcn_exp2f(s1[2]),
                                                   __builtin_amdgcn_exp2f(s1[3])));
        acc[t][0] = MFMA_BF16(e.v, bg0, acc[t][0], 0, 0, 0);
        acc[t][1] = MFMA_BF16(e.v, bg1, acc[t][1], 0, 0, 0);
        den[t]    = MFMA_BF16(e.v, ones, den[t], 0, 0, 0);
      }
    }
  }

  // ---- combine the two key-halves (cmb reuses staging LDS)
  __syncthreads();                          // all waves done reading g/phi LDS
  if (kh == 1) {
    #pragma unroll
    for (int t = 0; t < 2; ++t) {
      #pragma unroll
      for (int reg = 0; reg < 4; ++reg) {
        int row = rg*32 + t*16 + q*4 + reg;
        cmb[row*34 + r]      = acc[t][0][reg];
        cmb[row*34 + 16 + r] = acc[t][1][reg];
        if (r == 0) cmb[row*34 + 32] = den[t][reg];
      }
    }
  }
  __syncthreads();
  if (kh == 0) {
    #pragma unroll
    for (int t = 0; t < 2; ++t) {
      #pragma unroll
      for (int reg = 0; reg < 4; ++reg) {
        int row = rg*32 + t*16 + q*4 + reg;
        float o0 = acc[t][0][reg] + cmb[row*34 + r];
        float o1 = acc[t][1][reg] + cmb[row*34 + 16 + r];
        float dn = den[t][reg]    + cmb[row*34 + 32];
        float iv = __builtin_amdgcn_rcpf(dn);
        o_sh[row*33 + r]      = o0 * iv;
        o_sh[row*33 + 16 + r] = o1 * iv;
      }
    }
  }
  __syncthreads();

  // ---- epilogue: out[b,co,n0+rr] = gamma*(w_last[co,:].O[rr,:]+b_last[co])+x
  int rr  = tid & 127;
  int wqu = __builtin_amdgcn_readfirstlane(tid >> 7);  // 0..3, uniform
  float o_reg[32];
  #pragma unroll
  for (int c = 0; c < 32; ++c) o_reg[c] = o_sh[rr*33 + c];
  float gm = gamma[0];
  for (int i = 0; i < 16; ++i) {
    int co = wqu*16 + i;                     // uniform -> s_load weights
    const float* wl = w_last + co*32;
    float a = b_last[co];
    #pragma unroll
    for (int c = 0; c < 32; ++c) a += wl[c] * o_reg[c];
    size_t oi = ((size_t)b*C_ + co)*HW_ + (size_t)(n0 + rr);
    out[oi] = gm * a + x[oi];
  }
}

// ---------------------------------------------------------------------------
extern "C" void kernel_launch(void* const* d_in, const int* in_sizes, int n_in,
                              void* d_out, int out_size, void* d_ws, size_t ws_size,
                              hipStream_t stream) {
  const float* x       = (const float*)d_in[0];
  const float* w_delta = (const float*)d_in[1];
  const float* b_delta = (const float*)d_in[2];
  const float* w_phi   = (const float*)d_in[3];
  const float* b_phi   = (const float*)d_in[4];
  const float* w_g     = (const float*)d_in[5];
  const float* b_g     = (const float*)d_in[6];
  const float* w_last  = (const float*)d_in[7];
  const float* b_last  = (const float*)d_in[8];
  const float* gamma   = (const float*)d_in[9];
  float* out = (float*)d_out;

  unsigned short* ws = (unsigned short*)d_ws;
  unsigned short* phi_s   = ws;                                        // 0.5 MB
  unsigned short* g_t     = ws + (size_t)B_*M_*16;                     // 1 MB
  unsigned short* delta_s = ws + (size_t)B_*M_*16 + (size_t)B_*C2_*M_; // 2 MB

  hipLaunchKernelGGL(k_pre, dim3(1024), dim3(256), 0, stream,
                     x, w_delta, b_delta, w_phi, b_phi, w_g, b_g,
                     delta_s, phi_s, g_t);
  hipLaunchKernelGGL(k_attn, dim3(512), dim3(512), 0, stream,
                     x, delta_s, phi_s, g_t, w_last, b_last, gamma, out);
}